// Round 6
// baseline (3949.834 us; speedup 1.0000x reference)
//
#include <hip/hip_runtime.h>

#define NCLS 5
#define NQRY 75
#define NTOT 80            // N = 80
#define FD   640
#define HIDN 4096
#define DNIN 465
#define KPAD 512           // DNIN padded to 512 for MFMA K
#define NPAD 512           // DNIN padded for GEMM3 N
#define LRDNI 1e-3f

#define KS1 4              // K-splits layer1 (K=512  -> 4 ksteps each)
#define KS2 8              // K-splits layer2 (K=4096 -> 16 ksteps each)
#define KS3 32             // K-splits layer3 (K=4096 -> 4 ksteps each)

#define NBLK 256           // k_refine grid: 1 block/CU, co-residency guaranteed
#define BARSTRIDE 320      // ints per barrier slot (8 groups*32 + root@256 + go@288)
#define NBAR 64            // allocated barrier slots (54 used)

typedef short  v8s __attribute__((ext_vector_type(8)));
typedef float  v4f __attribute__((ext_vector_type(4)));

__device__ __forceinline__ ushort f2bf(float x) {
    uint u = __float_as_uint(x);
    u = (u + 0x7FFFu + ((u >> 16) & 1u)) >> 16;
    return (ushort)u;
}
__device__ __forceinline__ uint pk2(float a, float b) {
    return (uint)f2bf(a) | ((uint)f2bf(b) << 16);
}

// ================= setup: all weight converts (frag-major) + init ===============
// Fragment-major layout: B'[ntile][kstep][lane][8]; element (n,k) at
// ntile=n>>4, kstep=k>>5, lane=((k>>3)&3)*16+(n&15), j=k&7.
// Grid is EXACTLY 2048 blocks x 256 threads. Also zeroes the barrier slots.
__global__ __launch_bounds__(256) void k_setup(
                        const float* __restrict__ fs, const float* __restrict__ fq,
                        const float* __restrict__ W1s, const float* __restrict__ W1q,
                        const float* __restrict__ W2s, const float* __restrict__ W2q,
                        const float* __restrict__ W3s, const float* __restrict__ W3q,
                        ushort* __restrict__ W1bs, ushort* __restrict__ W1bq,
                        ushort* __restrict__ W2bs, ushort* __restrict__ W2bq,
                        ushort* __restrict__ W3bs, ushort* __restrict__ W3bq,
                        float* __restrict__ supp, float* __restrict__ qbuf,
                        int* __restrict__ bar) {
    int tid = blockIdx.x * 256 + threadIdx.x;      // 0 .. 524287

    if (tid < NBAR * BARSTRIDE) bar[tid] = 0;      // re-zeroed every replay

    // --- W2 [4096][4096] -> frag [256][128][64][8]: 2097152 octs per matrix.
    #pragma unroll
    for (int i = 0; i < 4; i++) {
        int oo = tid + i * 524288;
        int l = oo & 63, ks = (oo >> 6) & 127, nt = oo >> 13;
        int n = nt * 16 + (l & 15), kb = ks * 32 + ((l >> 4) << 3);
        size_t src = (size_t)n * HIDN + kb;
        float4 s0 = *(const float4*)(W2s + src);
        float4 s1 = *(const float4*)(W2s + src + 4);
        float4 t0 = *(const float4*)(W2q + src);
        float4 t1 = *(const float4*)(W2q + src + 4);
        uint4 qa, qb;
        qa.x = pk2(s0.x, s0.y); qa.y = pk2(s0.z, s0.w);
        qa.z = pk2(s1.x, s1.y); qa.w = pk2(s1.z, s1.w);
        qb.x = pk2(t0.x, t0.y); qb.y = pk2(t0.z, t0.w);
        qb.z = pk2(t1.x, t1.y); qb.w = pk2(t1.z, t1.w);
        *(uint4*)(W2bs + (size_t)oo * 8) = qa;
        *(uint4*)(W2bq + (size_t)oo * 8) = qb;
    }

    // --- W1 [4096][465] -> frag [256][16][64][8]: 262144 octs each, 1 per thread
    {
        int oo = tid & 262143;
        const float* Ws = (tid < 262144) ? W1s : W1q;
        ushort* Wd = (tid < 262144) ? W1bs : W1bq;
        int l = oo & 63, ks = (oo >> 6) & 15, nt = oo >> 10;
        int n = nt * 16 + (l & 15), kb = ks * 32 + ((l >> 4) << 3);
        ushort tmp[8];
        #pragma unroll
        for (int j = 0; j < 8; j++) {
            int k = kb + j;
            tmp[j] = (k < DNIN) ? f2bf(Ws[n * DNIN + k]) : (ushort)0;
        }
        *(uint4*)(Wd + (size_t)oo * 8) = *(uint4*)tmp;
    }

    // --- W3 [465][4096] -> frag [32][128][64][8]: 262144 octs each, 1 per thread
    {
        int oo = tid & 262143;
        const float* Ws = (tid < 262144) ? W3s : W3q;
        ushort* Wd = (tid < 262144) ? W3bs : W3bq;
        int l = oo & 63, ks = (oo >> 6) & 127, nt = oo >> 13;
        int n = nt * 16 + (l & 15), kb = ks * 32 + ((l >> 4) << 3);
        uint4 q;
        if (n < DNIN) {
            float4 f0 = *(const float4*)(Ws + (size_t)n * HIDN + kb);
            float4 f1 = *(const float4*)(Ws + (size_t)n * HIDN + kb + 4);
            q.x = pk2(f0.x, f0.y); q.y = pk2(f0.z, f0.w);
            q.z = pk2(f1.x, f1.y); q.w = pk2(f1.z, f1.w);
        } else q = (uint4){0, 0, 0, 0};
        *(uint4*)(Wd + (size_t)oo * 8) = q;
    }

    // --- init: supp = mean(fs, axis=1); qbuf = fq ---
    if (tid < NCLS * FD) {
        int c = tid / FD, d = tid % FD;
        float s = 0.f;
        #pragma unroll
        for (int t = 0; t < 5; t++) s += fs[(c * 5 + t) * FD + d];
        supp[tid] = s * 0.2f;
    }
    if (tid < NQRY * FD / 4)
        ((float4*)qbuf)[tid] = ((const float4*)fq)[tid];
}

// ====================== fused refine kernel (manual grid barrier) ===============

// Two-level device-scope barrier. Slot bix is used EXACTLY ONCE (monotone index,
// zeroed by k_setup) -> no sense reversal. Group = bid&7 (~XCD), 32 blocks each.
// Arrive: syncthreads -> t0 fence(release L2 writeback) -> group count; last of
// group bumps root; last group sets go. All t0 spin on go (acquire) -> fence.
__device__ __forceinline__ void gbar(int* bar, int bix) {
    __syncthreads();
    if (threadIdx.x == 0) {
        int* base = bar + bix * BARSTRIDE;
        __threadfence();   // agent-scope: writes back local L2 (cross-XCD release)
        int g = blockIdx.x & 7;
        if (__hip_atomic_fetch_add(base + g * 32, 1, __ATOMIC_ACQ_REL,
                                   __HIP_MEMORY_SCOPE_AGENT) == NBLK / 8 - 1) {
            if (__hip_atomic_fetch_add(base + 256, 1, __ATOMIC_ACQ_REL,
                                       __HIP_MEMORY_SCOPE_AGENT) == 7) {
                __hip_atomic_store(base + 288, 1, __ATOMIC_RELEASE,
                                   __HIP_MEMORY_SCOPE_AGENT);
            }
        }
        while (__hip_atomic_load(base + 288, __ATOMIC_ACQUIRE,
                                 __HIP_MEMORY_SCOPE_AGENT) == 0)
            __builtin_amdgcn_s_sleep(2);
        __threadfence();   // acquire side: invalidate local caches
    }
    __syncthreads();
}

struct SMem {
    union {
        struct { float fi[FD]; float row[NTOT]; float ssh[NTOT]; } sr;
        struct { int p[81]; } gp;
        struct { float cj[NTOT]; float red[2]; } bw;
    } u;
};

__device__ __forceinline__ const float* rowptr(const float* supp, const float* qbuf, int r) {
    return (r < NCLS) ? (supp + r * FD) : (qbuf + (r - NCLS) * FD);
}

// m -> (a,b): masked entries of 81x81, row-major; a in 0..5, b in a+1..80
__device__ __forceinline__ void mask_ab(int m, int& a, int& b) {
    int start = 0, len = 80, aa = 0;
    while (m >= start + len) { start += len; len--; aa++; }
    a = aa; b = aa + 1 + (m - start);
}

// ---- fused: norms + S = fn@fn^T + f (normalized) + stable rank -> perm --------
__device__ void simrank_body(SMem& sm, int i, bool fin,
        const float* supp, const float* qbuf, float* f, float* nrm,
        float* S, int* perm, const float* scale, float* out) {
    int t = threadIdx.x;               // 256 threads
    const float* ri = rowptr(supp, qbuf, i);
    for (int u = t; u < FD; u += 256) sm.u.sr.fi[u] = ri[u];
    __syncthreads();
    float dot = 0.f;
    if (t < NTOT) {
        const float* rj = rowptr(supp, qbuf, t);
        float ss = 0.f;
        for (int k = 0; k < FD; k += 4) {
            float4 a = *(const float4*)(sm.u.sr.fi + k);
            float4 b = *(const float4*)(rj + k);
            dot += a.x * b.x + a.y * b.y + a.z * b.z + a.w * b.w;
            ss  += b.x * b.x + b.y * b.y + b.z * b.z + b.w * b.w;
        }
        sm.u.sr.ssh[t] = ss;
    }
    __syncthreads();
    float ni = fmaxf(sqrtf(sm.u.sr.ssh[i]), 1e-12f);
    float inv_i = 1.0f / ni;
    if (t < NTOT) {
        float nt2 = fmaxf(sqrtf(sm.u.sr.ssh[t]), 1e-12f);
        float val = dot * inv_i / nt2;
        if (fin) {
            if (t >= NCLS) out[(t - NCLS) * NCLS + i] = val * scale[0];
        } else {
            sm.u.sr.row[t] = val;
            S[i * NTOT + t] = val;
        }
    }
    if (fin) return;                   // uniform per call site
    __syncthreads();
    for (int u = t; u < FD; u += 256) f[i * FD + u] = sm.u.sr.fi[u] * inv_i;
    if (t == 0) { nrm[i] = ni; perm[i * 81] = i; }
    if (t < NCLS) {
        float v = sm.u.sr.row[t]; int rank = 0;
        for (int k = 0; k < NCLS; k++) {
            float w = sm.u.sr.row[k];
            if (w > v || (w == v && k < t)) rank++;
        }
        perm[i * 81 + 1 + rank] = t;
    } else if (t < NTOT) {
        int j = t - NCLS; float v = sm.u.sr.row[t]; int rank = 0;
        for (int k = NCLS; k < NTOT; k++) {
            float w = sm.u.sr.row[k];
            if (w > v || (w == v && (k - NCLS) < j)) rank++;
        }
        perm[i * 81 + 6 + rank] = t;
    }
}

// ---------------- gather Xb[i][m] = bf16(S[p[a]][p[b]]) + zero Gs ----------------
__device__ void gather_body(SMem& sm, int i, const float* S, const int* perm,
                            ushort* Xb, float* Gs) {
    int t = threadIdx.x;
    if (t < 81) sm.u.gp.p[t] = perm[i * 81 + t];
    if (t < NTOT) Gs[i * NTOT + t] = 0.f;
    __syncthreads();
    for (int m = t; m < KPAD; m += 256) {
        if (m < DNIN) {
            int a, b; mask_ab(m, a, b);
            Xb[i * KPAD + m] = f2bf(S[sm.u.gp.p[a] * NTOT + sm.u.gp.p[b]]);
        } else Xb[i * KPAD + m] = 0;
    }
}

// ------- barrier-free MFMA GEMM partials, frag-major B, NT=1 --------------------
template<int KSTEPS>
__device__ void gemm_body(int bx, int ky, const ushort* __restrict__ A, int lda,
                          const ushort* __restrict__ Bf, int nks,
                          float* __restrict__ C, int ldc) {
    int tid = threadIdx.x;
    int w = tid >> 6, lane = tid & 63, l16 = lane & 15, quad = lane >> 4;
    int n0 = bx * 64 + w * 16;
    int kc0 = ky * (KSTEPS * 32);
    const ushort* Ap = A + l16 * lda + kc0 + quad * 8;
    const ushort* Bp = Bf + ((size_t)(n0 >> 4) * nks + (kc0 >> 5)) * 512 + lane * 8;

    v4f acc[5];
    #pragma unroll
    for (int mt = 0; mt < 5; mt++) acc[mt] = (v4f){0.f, 0.f, 0.f, 0.f};

    #pragma unroll
    for (int s = 0; s < KSTEPS; s++) {
        v8s a[5], b;
        #pragma unroll
        for (int mt = 0; mt < 5; mt++)
            a[mt] = *(const v8s*)(Ap + mt * 16 * lda + s * 32);
        b = *(const v8s*)(Bp + (size_t)s * 512);
        #pragma unroll
        for (int mt = 0; mt < 5; mt++)
            acc[mt] = __builtin_amdgcn_mfma_f32_16x16x32_bf16(a[mt], b, acc[mt], 0, 0, 0);
    }
    float* Cp = C + (size_t)ky * 80 * ldc;
    int col = n0 + l16;
    #pragma unroll
    for (int mt = 0; mt < 5; mt++)
        #pragma unroll
        for (int r = 0; r < 4; r++)
            Cp[(mt * 16 + quad * 4 + r) * ldc + col] = acc[mt][r];
}

// ---------------- H = bf16(relu(sum_ks P + bias))  (80 x 4096, x4 vectorized) ----
template<int NS>
__device__ void ep_body(int idx, const float* P, const float* bias, ushort* H) {
    if (idx >= 80 * HIDN / 4) return;
    float4 s = ((const float4*)bias)[idx & 1023];
    #pragma unroll
    for (int ks = 0; ks < NS; ks++) {
        float4 p = ((const float4*)P)[(size_t)ks * (80 * HIDN / 4) + idx];
        s.x += p.x; s.y += p.y; s.z += p.z; s.w += p.w;
    }
    uint2 q;
    q.x = pk2(fmaxf(s.x, 0.f), fmaxf(s.y, 0.f));
    q.y = pk2(fmaxf(s.z, 0.f), fmaxf(s.w, 0.f));
    ((uint2*)H)[idx] = q;
}

// ---------------- scatter-add VJP of the gather (sums P3 partials + b3) --------
__device__ void scatter_body(SMem& sm, int i, const float* P3, const float* b3,
                             const int* perm, float* Gs) {
    int t = threadIdx.x;
    if (t < 81) sm.u.gp.p[t] = perm[i * 81 + t];
    __syncthreads();
    for (int m = t; m < DNIN; m += 256) {
        float g = b3[m];
        #pragma unroll
        for (int ks = 0; ks < KS3; ks++) g += P3[(size_t)ks * (80 * NPAD) + i * NPAD + m];
        int a, b; mask_ab(m, a, b);
        atomicAdd(&Gs[sm.u.gp.p[a] * NTOT + sm.u.gp.p[b]], g);
    }
}

// ---- dfeat = (Gs+Gs^T) @ f ; dx = (dfeat - (dfeat.f) f)/n ; dst -= LR*dx ------
__device__ void bwd_body(SMem& sm, int r, const float* Gs, const float* f,
                         const float* nrm, float* dst) {
    int t = threadIdx.x;
    if (t < NTOT) sm.u.bw.cj[t] = Gs[r * NTOT + t] + Gs[t * NTOT + r];
    __syncthreads();
    float df[5] = {0.f, 0.f, 0.f, 0.f, 0.f};
    float frv[5];
    if (t < 128) {
        for (int j = 0; j < NTOT; j++) {
            float c = sm.u.bw.cj[j];
            const float* fj = f + j * FD;
            #pragma unroll
            for (int u = 0; u < 5; u++) df[u] += c * fj[t + 128 * u];
        }
        const float* fr = f + r * FD;
        float partial = 0.f;
        #pragma unroll
        for (int u = 0; u < 5; u++) { frv[u] = fr[t + 128 * u]; partial += df[u] * frv[u]; }
        #pragma unroll
        for (int o = 32; o > 0; o >>= 1) partial += __shfl_xor(partial, o, 64);
        if ((t & 63) == 0) sm.u.bw.red[t >> 6] = partial;
    }
    __syncthreads();
    if (t < 128) {
        float dotv = sm.u.bw.red[0] + sm.u.bw.red[1];
        float invn = 1.0f / nrm[r];
        #pragma unroll
        for (int u = 0; u < 5; u++) {
            float dx = (df[u] - dotv * frv[u]) * invn;
            dst[t + 128 * u] -= LRDNI * dx;
        }
    }
}

// One kernel = entire 3-step refine loop + final FIN pass.
// grid MUST be NBLK=256 blocks x 256 threads (1 block/CU -> all co-resident).
__global__ __launch_bounds__(256) void k_refine(
        float* ws, const float* b1s, const float* b2s, const float* b3s,
        const float* b1q, const float* b2q, const float* b3q,
        const float* scale, float* out) {
    __shared__ SMem sm;
    int bid = blockIdx.x;
    int t = threadIdx.x;

    // derive workspace pointers (same arithmetic as host)
    float* supp = ws;                       // 3200
    float* qbuf = supp + 3200;              // 48000
    float* f    = qbuf + 48000;             // 51200
    float* nrm  = f + 51200;                // 96 (pad)
    float* S    = nrm + 96;                 // 6400
    int*   perm = (int*)(S + 6400);         // 6480 -> pad 6496
    float* P1   = (float*)(perm + 6496);
    float* P2   = P1 + (size_t)KS1 * 80 * HIDN;
    float* P3   = P2 + (size_t)KS2 * 80 * HIDN;
    float* Gs   = P3 + (size_t)KS3 * 80 * NPAD;
    ushort* Xb  = (ushort*)(Gs + 6400);
    ushort* H1b = Xb + 80 * KPAD;
    ushort* H2b = H1b + 80 * HIDN;
    ushort* W1b_ds = H2b + 80 * HIDN;
    ushort* W1b_dq = W1b_ds + HIDN * KPAD;
    ushort* W3b_ds = W1b_dq + HIDN * KPAD;
    ushort* W3b_dq = W3b_ds + NPAD * HIDN;
    ushort* W2b_ds = W3b_dq + NPAD * HIDN;
    ushort* W2b_dq = W2b_ds + (size_t)HIDN * HIDN;
    int* bar = (int*)(W2b_dq + (size_t)HIDN * HIDN);

    int bix = 0;
    for (int step = 0; step < 3; step++) {
        for (int half = 0; half < 2; half++) {
            const float* b1 = half ? b1q : b1s;
            const float* b2 = half ? b2q : b2s;
            const float* b3 = half ? b3q : b3s;
            const ushort* W1b = half ? W1b_dq : W1b_ds;
            const ushort* W2b = half ? W2b_dq : W2b_ds;
            const ushort* W3b = half ? W3b_dq : W3b_ds;

            if (bid < 80)
                simrank_body(sm, bid, false, supp, qbuf, f, nrm, S, perm, nullptr, nullptr);
            gbar(bar, bix++);
            if (bid < 80)
                gather_body(sm, bid, S, perm, Xb, Gs);
            gbar(bar, bix++);
            // L1: M=80 N=4096 K=512; 64 x KS1 = 256 units, 1 per block
            gemm_body<4>(bid & 63, bid >> 6, Xb, KPAD, W1b, 16, P1, HIDN);
            gbar(bar, bix++);
            ep_body<KS1>(bid * 256 + t, P1, b1, H1b);
            ep_body<KS1>(65536 + bid * 256 + t, P1, b1, H1b);
            gbar(bar, bix++);
            // L2: M=80 N=4096 K=4096; 64 x KS2 = 512 units, 2 per block
            gemm_body<16>(bid & 63, bid >> 6, H1b, HIDN, W2b, 128, P2, HIDN);
            gemm_body<16>(bid & 63, 4 + (bid >> 6), H1b, HIDN, W2b, 128, P2, HIDN);
            gbar(bar, bix++);
            ep_body<KS2>(bid * 256 + t, P2, b2, H2b);
            ep_body<KS2>(65536 + bid * 256 + t, P2, b2, H2b);
            gbar(bar, bix++);
            // L3: M=80 N=512 K=4096; 8 x KS3 = 256 units, 1 per block
            gemm_body<4>(bid & 7, bid >> 3, H2b, HIDN, W3b, 128, P3, NPAD);
            gbar(bar, bix++);
            if (bid < 80)
                scatter_body(sm, bid, P3, b3, perm, Gs);
            gbar(bar, bix++);
            if (half == 0) {
                if (bid < 5)  bwd_body(sm, bid, Gs, f, nrm, supp + bid * FD);
            } else {
                if (bid < 75) bwd_body(sm, NCLS + bid, Gs, f, nrm, qbuf + bid * FD);
            }
            gbar(bar, bix++);
        }
    }
    if (bid < 5)
        simrank_body(sm, bid, true, supp, qbuf, f, nrm, S, perm, scale, out);
}

extern "C" void kernel_launch(void* const* d_in, const int* in_sizes, int n_in,
                              void* d_out, int out_size, void* d_ws, size_t ws_size,
                              hipStream_t stream) {
    const float* fs    = (const float*)d_in[0];
    const float* fq    = (const float*)d_in[1];
    const float* scale = (const float*)d_in[2];
    const float* W[12];
    for (int i = 0; i < 12; i++) W[i] = (const float*)d_in[3 + i];
    // W[0..5] = ds_{W1,b1,W2,b2,W3,b3}; W[6..11] = dq_*

    float* base = (float*)d_ws;
    float* supp = base;
    float* qbuf = supp + 3200;
    float* f    = qbuf + 48000;
    float* nrm  = f + 51200;
    float* S    = nrm + 96;
    int*   perm = (int*)(S + 6400);
    float* P1   = (float*)(perm + 6496);
    float* P2   = P1 + (size_t)KS1 * 80 * HIDN;
    float* P3   = P2 + (size_t)KS2 * 80 * HIDN;
    float* Gs   = P3 + (size_t)KS3 * 80 * NPAD;
    ushort* Xb  = (ushort*)(Gs + 6400);
    ushort* H1b = Xb + 80 * KPAD;
    ushort* H2b = H1b + 80 * HIDN;
    ushort* W1b_ds = H2b + 80 * HIDN;
    ushort* W1b_dq = W1b_ds + HIDN * KPAD;
    ushort* W3b_ds = W1b_dq + HIDN * KPAD;
    ushort* W3b_dq = W3b_ds + NPAD * HIDN;
    ushort* W2b_ds = W3b_dq + NPAD * HIDN;
    ushort* W2b_dq = W2b_ds + (size_t)HIDN * HIDN;
    int*    bar    = (int*)(W2b_dq + (size_t)HIDN * HIDN);

    // grid MUST be exactly 2048 blocks (k_setup assumes 524288 threads)
    k_setup<<<2048, 256, 0, stream>>>(fs, fq, W[0], W[6], W[2], W[8], W[4], W[10],
                                      W1b_ds, W1b_dq, W2b_ds, W2b_dq, W3b_ds, W3b_dq,
                                      supp, qbuf, bar);

    k_refine<<<NBLK, 256, 0, stream>>>((float*)d_ws, W[1], W[3], W[5],
                                       W[7], W[9], W[11], scale, (float*)d_out);
}

// Round 7
// 731.833 us; speedup vs baseline: 5.3972x; 5.3972x over previous
//
#include <hip/hip_runtime.h>

#define NCLS 5
#define NQRY 75
#define NTOT 80            // N = 80
#define FD   640
#define HIDN 4096
#define DNIN 465
#define KPAD 512           // DNIN padded to 512 for MFMA K
#define NPAD 512           // DNIN padded for GEMM3 N
#define LRDNI 1e-3f

typedef short  v8s __attribute__((ext_vector_type(8)));
typedef float  v4f __attribute__((ext_vector_type(4)));

__device__ __forceinline__ ushort f2bf(float x) {
    uint u = __float_as_uint(x);
    u = (u + 0x7FFFu + ((u >> 16) & 1u)) >> 16;
    return (ushort)u;
}
__device__ __forceinline__ uint pk2(float a, float b) {
    return (uint)f2bf(a) | ((uint)f2bf(b) << 16);
}

// ================= setup: all weight converts (frag-major) + init ===============
// Fragment-major layout: B'[ntile][kstep][lane][8]; element (n,k) at
// ntile=n>>4, kstep=k>>5, lane=((k>>3)&3)*16+(n&15), j=k&7.
// Grid is EXACTLY 2048 blocks x 256 threads. (Parked at ~77us: three access
// patterns all measured 2.0-2.2 TB/s -> chip-level limit for this op.)
__global__ __launch_bounds__(256) void k_setup(
                        const float* __restrict__ fs, const float* __restrict__ fq,
                        const float* __restrict__ W1s, const float* __restrict__ W1q,
                        const float* __restrict__ W2s, const float* __restrict__ W2q,
                        const float* __restrict__ W3s, const float* __restrict__ W3q,
                        ushort* __restrict__ W1bs, ushort* __restrict__ W1bq,
                        ushort* __restrict__ W2bs, ushort* __restrict__ W2bq,
                        ushort* __restrict__ W3bs, ushort* __restrict__ W3bq,
                        float* __restrict__ supp, float* __restrict__ qbuf) {
    int tid = blockIdx.x * 256 + threadIdx.x;      // 0 .. 524287

    // --- W2 [4096][4096] -> frag [256][128][64][8]: 2097152 octs per matrix.
    #pragma unroll
    for (int i = 0; i < 4; i++) {
        int oo = tid + i * 524288;
        int l = oo & 63, ks = (oo >> 6) & 127, nt = oo >> 13;
        int n = nt * 16 + (l & 15), kb = ks * 32 + ((l >> 4) << 3);
        size_t src = (size_t)n * HIDN + kb;
        float4 s0 = *(const float4*)(W2s + src);
        float4 s1 = *(const float4*)(W2s + src + 4);
        float4 t0 = *(const float4*)(W2q + src);
        float4 t1 = *(const float4*)(W2q + src + 4);
        uint4 qa, qb;
        qa.x = pk2(s0.x, s0.y); qa.y = pk2(s0.z, s0.w);
        qa.z = pk2(s1.x, s1.y); qa.w = pk2(s1.z, s1.w);
        qb.x = pk2(t0.x, t0.y); qb.y = pk2(t0.z, t0.w);
        qb.z = pk2(t1.x, t1.y); qb.w = pk2(t1.z, t1.w);
        *(uint4*)(W2bs + (size_t)oo * 8) = qa;
        *(uint4*)(W2bq + (size_t)oo * 8) = qb;
    }

    // --- W1 [4096][465] -> frag [256][16][64][8]: 262144 octs each, 1 per thread
    {
        int oo = tid & 262143;
        const float* Ws = (tid < 262144) ? W1s : W1q;
        ushort* Wd = (tid < 262144) ? W1bs : W1bq;
        int l = oo & 63, ks = (oo >> 6) & 15, nt = oo >> 10;
        int n = nt * 16 + (l & 15), kb = ks * 32 + ((l >> 4) << 3);
        ushort tmp[8];
        #pragma unroll
        for (int j = 0; j < 8; j++) {
            int k = kb + j;
            tmp[j] = (k < DNIN) ? f2bf(Ws[n * DNIN + k]) : (ushort)0;
        }
        *(uint4*)(Wd + (size_t)oo * 8) = *(uint4*)tmp;
    }

    // --- W3 [465][4096] -> frag [32][128][64][8]: 262144 octs each, 1 per thread
    {
        int oo = tid & 262143;
        const float* Ws = (tid < 262144) ? W3s : W3q;
        ushort* Wd = (tid < 262144) ? W3bs : W3bq;
        int l = oo & 63, ks = (oo >> 6) & 127, nt = oo >> 13;
        int n = nt * 16 + (l & 15), kb = ks * 32 + ((l >> 4) << 3);
        uint4 q;
        if (n < DNIN) {
            float4 f0 = *(const float4*)(Ws + (size_t)n * HIDN + kb);
            float4 f1 = *(const float4*)(Ws + (size_t)n * HIDN + kb + 4);
            q.x = pk2(f0.x, f0.y); q.y = pk2(f0.z, f0.w);
            q.z = pk2(f1.x, f1.y); q.w = pk2(f1.z, f1.w);
        } else q = (uint4){0, 0, 0, 0};
        *(uint4*)(Wd + (size_t)oo * 8) = q;
    }

    // --- init: supp = mean(fs, axis=1); qbuf = fq ---
    if (tid < NCLS * FD) {
        int c = tid / FD, d = tid % FD;
        float s = 0.f;
        #pragma unroll
        for (int t = 0; t < 5; t++) s += fs[(c * 5 + t) * FD + d];
        supp[tid] = s * 0.2f;
    }
    if (tid < NQRY * FD / 4)
        ((float4*)qbuf)[tid] = ((const float4*)fq)[tid];
}

__device__ __forceinline__ const float* rowptr(const float* supp, const float* qbuf, int r) {
    return (r < NCLS) ? (supp + r * FD) : (qbuf + (r - NCLS) * FD);
}

// ---- fused: norms + S = fn@fn^T + f (normalized) + stable rank -> perm --------
// FIN variant: only writes out[j*5+i] = S[i][5+j]*scale  (grid = 5 blocks)
template<bool FIN>
__global__ void k_simrank(const float* __restrict__ supp, const float* __restrict__ qbuf,
                          float* __restrict__ f, float* __restrict__ nrm,
                          float* __restrict__ S, int* __restrict__ perm,
                          const float* __restrict__ scale, float* __restrict__ out) {
    __shared__ float fi[FD];
    __shared__ float row[NTOT];
    __shared__ float ssh[NTOT];
    int i = blockIdx.x;
    int t = threadIdx.x;                // 128
    const float* ri = rowptr(supp, qbuf, i);
    for (int u = t; u < FD; u += 128) fi[u] = ri[u];
    __syncthreads();
    float dot = 0.f;
    if (t < NTOT) {
        const float* rj = rowptr(supp, qbuf, t);
        float ss = 0.f;
        for (int k = 0; k < FD; k += 4) {
            float4 a = *(const float4*)(fi + k);
            float4 b = *(const float4*)(rj + k);
            dot += a.x * b.x + a.y * b.y + a.z * b.z + a.w * b.w;
            ss  += b.x * b.x + b.y * b.y + b.z * b.z + b.w * b.w;
        }
        ssh[t] = ss;
    }
    __syncthreads();
    float ni = fmaxf(sqrtf(ssh[i]), 1e-12f);
    float inv_i = 1.0f / ni;
    if (t < NTOT) {
        float nt = fmaxf(sqrtf(ssh[t]), 1e-12f);
        float val = dot * inv_i / nt;
        if (FIN) {
            if (t >= NCLS) out[(t - NCLS) * NCLS + i] = val * scale[0];
        } else {
            row[t] = val;
            S[i * NTOT + t] = val;
        }
    }
    if (FIN) return;
    __syncthreads();
    for (int u = t; u < FD; u += 128) f[i * FD + u] = fi[u] * inv_i;
    if (t == 0) { nrm[i] = ni; perm[i * 81] = i; }
    if (t < NCLS) {
        float v = row[t]; int rank = 0;
        for (int k = 0; k < NCLS; k++) {
            float w = row[k];
            if (w > v || (w == v && k < t)) rank++;
        }
        perm[i * 81 + 1 + rank] = t;
    } else if (t < NTOT) {
        int j = t - NCLS; float v = row[t]; int rank = 0;
        for (int k = NCLS; k < NTOT; k++) {
            float w = row[k];
            if (w > v || (w == v && (k - NCLS) < j)) rank++;
        }
        perm[i * 81 + 6 + rank] = t;
    }
}

// m -> (a,b): masked entries of 81x81, row-major; a in 0..5, b in a+1..80
__device__ __forceinline__ void mask_ab(int m, int& a, int& b) {
    int start = 0, len = 80, aa = 0;
    while (m >= start + len) { start += len; len--; aa++; }
    a = aa; b = aa + 1 + (m - start);
}

// ---------------- gather Xb[i][m] = bf16(S[p[a]][p[b]]) + zero Gs ----------------
__global__ void k_gather(const float* __restrict__ S, const int* __restrict__ perm,
                         ushort* __restrict__ Xb, float* __restrict__ Gs) {
    __shared__ int p[81];
    int i = blockIdx.x;
    int t = threadIdx.x;                // 512
    if (t < 81) p[t] = perm[i * 81 + t];
    if (t < NTOT) Gs[i * NTOT + t] = 0.f;
    __syncthreads();
    if (t < DNIN) {
        int a, b; mask_ab(t, a, b);
        Xb[i * KPAD + t] = f2bf(S[p[a] * NTOT + p[b]]);
    } else if (t < KPAD) {
        Xb[i * KPAD + t] = 0;
    }
}

// ------- wave-split-K MFMA GEMM with in-block reduction + fused epilogue --------
// Block = 16 output cols x 80 rows x FULL K. WAVES waves each take a K-slice of
// KPW ksteps (K = WAVES*KPW*32), accumulate in AGPRs, reduce via LDS, then:
//   EPI=true : H[row][n0+col] = bf16(relu(sum + bias[n0+col]))   (ldh = HIDN)
//   EPI=false: C[row][n0+col] = sum                              (ldc = ldcp)
// B is fragment-major (see k_setup) -> every B load is a contiguous 1KB segment.
template<int WAVES, int KPW, bool EPI>
__global__ __launch_bounds__(WAVES * 64) void k_gemmws(
        const ushort* __restrict__ A, int lda,
        const ushort* __restrict__ Bf, int nks,
        const float* __restrict__ bias, ushort* __restrict__ H,
        float* __restrict__ C, int ldcp) {
    __shared__ v4f red[WAVES][5][64];
    int t = threadIdx.x;
    int w = t >> 6, lane = t & 63, l16 = lane & 15, quad = lane >> 4;
    int n0 = blockIdx.x * 16;
    int kc0 = w * (KPW * 32);
    const ushort* Ap = A + l16 * lda + kc0 + quad * 8;
    const ushort* Bp = Bf + ((size_t)blockIdx.x * nks + (kc0 >> 5)) * 512 + lane * 8;

    v4f acc[5];
    #pragma unroll
    for (int mt = 0; mt < 5; mt++) acc[mt] = (v4f){0.f, 0.f, 0.f, 0.f};

    #pragma unroll
    for (int s = 0; s < KPW; s++) {
        v8s a[5], b;
        #pragma unroll
        for (int mt = 0; mt < 5; mt++)
            a[mt] = *(const v8s*)(Ap + mt * 16 * lda + s * 32);
        b = *(const v8s*)(Bp + (size_t)s * 512);
        #pragma unroll
        for (int mt = 0; mt < 5; mt++)
            acc[mt] = __builtin_amdgcn_mfma_f32_16x16x32_bf16(a[mt], b, acc[mt], 0, 0, 0);
    }
    #pragma unroll
    for (int mt = 0; mt < 5; mt++) red[w][mt][lane] = acc[mt];
    __syncthreads();

    // reduce + epilogue: 80 rows x 16 cols; acc elem (mt,quad,r,l16) is
    // row = mt*16 + quad*4 + r, col = l16.
    #pragma unroll
    for (int j = 0; j < (1280 + WAVES * 64 - 1) / (WAVES * 64); j++) {
        int row = j * (WAVES * 4) + (t >> 4);
        if (row < 80) {
            int col = t & 15;
            int mt = row >> 4, rr = row & 15, qq = rr >> 2, r = rr & 3;
            int ln = qq * 16 + col;
            float v = 0.f;
            #pragma unroll
            for (int w2 = 0; w2 < WAVES; w2++) v += red[w2][mt][ln][r];
            if (EPI) {
                v += bias[n0 + col];
                H[(size_t)row * HIDN + n0 + col] = f2bf(fmaxf(v, 0.f));
            } else {
                C[(size_t)row * ldcp + n0 + col] = v;
            }
        }
    }
}

// ---------------- scatter-add VJP of the gather (single P3 partial + b3) --------
__global__ void k_scatter(const float* __restrict__ P3, const float* __restrict__ b3,
                          const int* __restrict__ perm, float* __restrict__ Gs) {
    __shared__ int p[81];
    int i = blockIdx.x;
    int t = threadIdx.x;                // 512
    if (t < 81) p[t] = perm[i * 81 + t];
    __syncthreads();
    if (t < DNIN) {
        float g = b3[t] + P3[i * NPAD + t];
        int a, b; mask_ab(t, a, b);
        atomicAdd(&Gs[p[a] * NTOT + p[b]], g);
    }
}

// ---- dfeat = (Gs+Gs^T) @ f ; dx = (dfeat - (dfeat.f) f)/n ; target -= LR*dx ----
__global__ void k_bwd(const float* __restrict__ Gs, const float* __restrict__ f,
                      const float* __restrict__ nrm, float* __restrict__ target,
                      int row0) {
    int r = row0 + blockIdx.x;
    __shared__ float cj[NTOT];
    __shared__ float red[2];
    int t = threadIdx.x;                // 128 threads, 5 elems each
    if (t < NTOT) cj[t] = Gs[r * NTOT + t] + Gs[t * NTOT + r];
    __syncthreads();
    float df[5] = {0.f, 0.f, 0.f, 0.f, 0.f};
    for (int j = 0; j < NTOT; j++) {
        float c = cj[j];
        const float* fj = f + j * FD;
        #pragma unroll
        for (int u = 0; u < 5; u++) df[u] += c * fj[t + 128 * u];
    }
    const float* fr = f + r * FD;
    float frv[5]; float partial = 0.f;
    #pragma unroll
    for (int u = 0; u < 5; u++) { frv[u] = fr[t + 128 * u]; partial += df[u] * frv[u]; }
    #pragma unroll
    for (int o = 32; o > 0; o >>= 1) partial += __shfl_xor(partial, o, 64);
    if ((t & 63) == 0) red[t >> 6] = partial;
    __syncthreads();
    float dot = red[0] + red[1];
    float invn = 1.0f / nrm[r];
    float* dst = target + blockIdx.x * FD;
    #pragma unroll
    for (int u = 0; u < 5; u++) {
        float dx = (df[u] - dot * frv[u]) * invn;
        dst[t + 128 * u] -= LRDNI * dx;
    }
}

extern "C" void kernel_launch(void* const* d_in, const int* in_sizes, int n_in,
                              void* d_out, int out_size, void* d_ws, size_t ws_size,
                              hipStream_t stream) {
    const float* fs    = (const float*)d_in[0];
    const float* fq    = (const float*)d_in[1];
    const float* scale = (const float*)d_in[2];
    const float* W[12];
    for (int i = 0; i < 12; i++) W[i] = (const float*)d_in[3 + i];
    // W[0..5] = ds_{W1,b1,W2,b2,W3,b3}; W[6..11] = dq_*

    float* base = (float*)d_ws;
    float* supp = base;                     // 3200
    float* qbuf = supp + 3200;              // 48000
    float* f    = qbuf + 48000;             // 51200
    float* nrm  = f + 51200;                // 96 (pad)
    float* S    = nrm + 96;                 // 6400
    int*   perm = (int*)(S + 6400);         // 6480 -> pad 6496
    float* P3   = (float*)(perm + 6496);    // 80*512 (single partial)
    float* Gs   = P3 + 80 * NPAD;           // 6400
    ushort* Xb  = (ushort*)(Gs + 6400);     // 80*512
    ushort* H1b = Xb + 80 * KPAD;           // 80*4096
    ushort* H2b = H1b + 80 * HIDN;          // 80*4096
    ushort* W1b_ds = H2b + 80 * HIDN;       // 4096*512 (frag-major)
    ushort* W1b_dq = W1b_ds + HIDN * KPAD;
    ushort* W3b_ds = W1b_dq + HIDN * KPAD;  // 512*4096 (frag-major)
    ushort* W3b_dq = W3b_ds + NPAD * HIDN;
    ushort* W2b_ds = W3b_dq + NPAD * HIDN;  // 4096*4096 (frag-major)
    ushort* W2b_dq = W2b_ds + (size_t)HIDN * HIDN;

    // grid MUST be exactly 2048 blocks (k_setup assumes 524288 threads)
    k_setup<<<2048, 256, 0, stream>>>(fs, fq, W[0], W[6], W[2], W[8], W[4], W[10],
                                      W1b_ds, W1b_dq, W2b_ds, W2b_dq, W3b_ds, W3b_dq,
                                      supp, qbuf);

    for (int step = 0; step < 3; step++) {
        for (int half = 0; half < 2; half++) {
            const float* const* w = (half == 0) ? W : (W + 6);
            const ushort* W1b = (half == 0) ? W1b_ds : W1b_dq;
            const ushort* W2b = (half == 0) ? W2b_ds : W2b_dq;
            const ushort* W3b = (half == 0) ? W3b_ds : W3b_dq;
            k_simrank<false><<<80, 128, 0, stream>>>(supp, qbuf, f, nrm, S, perm, nullptr, nullptr);
            k_gather<<<80, 512, 0, stream>>>(S, perm, Xb, Gs);
            // L1: M=80 N=4096 K=512;  256 blocks, 4 waves x 4 ksteps, epi->H1b
            k_gemmws<4, 4, true><<<256, 256, 0, stream>>>(
                Xb, KPAD, W1b, 16, w[1], H1b, nullptr, 0);
            // L2: M=80 N=4096 K=4096; 256 blocks, 4 waves x 32 ksteps, epi->H2b
            k_gemmws<4, 32, true><<<256, 256, 0, stream>>>(
                H1b, HIDN, W2b, 128, w[3], H2b, nullptr, 0);
            // L3: M=80 N=512 K=4096;  32 blocks, 8 waves x 16 ksteps, fp32->P3
            k_gemmws<8, 16, false><<<32, 512, 0, stream>>>(
                H2b, HIDN, W3b, 128, nullptr, nullptr, P3, NPAD);
            k_scatter<<<80, 512, 0, stream>>>(P3, w[5], perm, Gs);
            if (half == 0) k_bwd<<<5, 128, 0, stream>>>(Gs, f, nrm, supp, 0);
            else           k_bwd<<<75, 128, 0, stream>>>(Gs, f, nrm, qbuf, NCLS);
        }
    }
    k_simrank<true><<<5, 128, 0, stream>>>(supp, qbuf, f, nrm, S, perm, scale, (float*)d_out);
}

// Round 8
// 638.797 us; speedup vs baseline: 6.1832x; 1.1456x over previous
//
#include <hip/hip_runtime.h>

#define NCLS 5
#define NQRY 75
#define NTOT 80            // N = 80
#define FD   640
#define HIDN 4096
#define DNIN 465
#define KPAD 512           // DNIN padded to 512 for MFMA K
#define NPAD 512           // DNIN padded for GEMM3 N
#define LRDNI 1e-3f

typedef short  v8s __attribute__((ext_vector_type(8)));
typedef float  v4f __attribute__((ext_vector_type(4)));

__device__ __forceinline__ ushort f2bf(float x) {
    uint u = __float_as_uint(x);
    u = (u + 0x7FFFu + ((u >> 16) & 1u)) >> 16;
    return (ushort)u;
}
__device__ __forceinline__ uint pk2(float a, float b) {
    return (uint)f2bf(a) | ((uint)f2bf(b) << 16);
}

// ================= setup: all weight converts (frag-major) + init ===============
// Fragment-major layout: B'[ntile][kstep][lane][8]; element (n,k) at
// ntile=n>>4, kstep=k>>5, lane=((k>>3)&3)*16+(n&15), j=k&7.
// Grid is EXACTLY 2048 blocks x 256 threads. (Parked at ~77us: three access
// patterns all measured 2.0-2.2 TB/s -> chip-level limit for this op.)
__global__ __launch_bounds__(256) void k_setup(
                        const float* __restrict__ fs, const float* __restrict__ fq,
                        const float* __restrict__ W1s, const float* __restrict__ W1q,
                        const float* __restrict__ W2s, const float* __restrict__ W2q,
                        const float* __restrict__ W3s, const float* __restrict__ W3q,
                        ushort* __restrict__ W1bs, ushort* __restrict__ W1bq,
                        ushort* __restrict__ W2bs, ushort* __restrict__ W2bq,
                        ushort* __restrict__ W3bs, ushort* __restrict__ W3bq,
                        float* __restrict__ supp, float* __restrict__ qbuf) {
    int tid = blockIdx.x * 256 + threadIdx.x;      // 0 .. 524287

    // --- W2 [4096][4096] -> frag [256][128][64][8]: 2097152 octs per matrix.
    #pragma unroll
    for (int i = 0; i < 4; i++) {
        int oo = tid + i * 524288;
        int l = oo & 63, ks = (oo >> 6) & 127, nt = oo >> 13;
        int n = nt * 16 + (l & 15), kb = ks * 32 + ((l >> 4) << 3);
        size_t src = (size_t)n * HIDN + kb;
        float4 s0 = *(const float4*)(W2s + src);
        float4 s1 = *(const float4*)(W2s + src + 4);
        float4 t0 = *(const float4*)(W2q + src);
        float4 t1 = *(const float4*)(W2q + src + 4);
        uint4 qa, qb;
        qa.x = pk2(s0.x, s0.y); qa.y = pk2(s0.z, s0.w);
        qa.z = pk2(s1.x, s1.y); qa.w = pk2(s1.z, s1.w);
        qb.x = pk2(t0.x, t0.y); qb.y = pk2(t0.z, t0.w);
        qb.z = pk2(t1.x, t1.y); qb.w = pk2(t1.z, t1.w);
        *(uint4*)(W2bs + (size_t)oo * 8) = qa;
        *(uint4*)(W2bq + (size_t)oo * 8) = qb;
    }

    // --- W1 [4096][465] -> frag [256][16][64][8]: 262144 octs each, 1 per thread
    {
        int oo = tid & 262143;
        const float* Ws = (tid < 262144) ? W1s : W1q;
        ushort* Wd = (tid < 262144) ? W1bs : W1bq;
        int l = oo & 63, ks = (oo >> 6) & 15, nt = oo >> 10;
        int n = nt * 16 + (l & 15), kb = ks * 32 + ((l >> 4) << 3);
        ushort tmp[8];
        #pragma unroll
        for (int j = 0; j < 8; j++) {
            int k = kb + j;
            tmp[j] = (k < DNIN) ? f2bf(Ws[n * DNIN + k]) : (ushort)0;
        }
        *(uint4*)(Wd + (size_t)oo * 8) = *(uint4*)tmp;
    }

    // --- W3 [465][4096] -> frag [32][128][64][8]: 262144 octs each, 1 per thread
    {
        int oo = tid & 262143;
        const float* Ws = (tid < 262144) ? W3s : W3q;
        ushort* Wd = (tid < 262144) ? W3bs : W3bq;
        int l = oo & 63, ks = (oo >> 6) & 127, nt = oo >> 13;
        int n = nt * 16 + (l & 15), kb = ks * 32 + ((l >> 4) << 3);
        uint4 q;
        if (n < DNIN) {
            float4 f0 = *(const float4*)(Ws + (size_t)n * HIDN + kb);
            float4 f1 = *(const float4*)(Ws + (size_t)n * HIDN + kb + 4);
            q.x = pk2(f0.x, f0.y); q.y = pk2(f0.z, f0.w);
            q.z = pk2(f1.x, f1.y); q.w = pk2(f1.z, f1.w);
        } else q = (uint4){0, 0, 0, 0};
        *(uint4*)(Wd + (size_t)oo * 8) = q;
    }

    // --- init: supp = mean(fs, axis=1); qbuf = fq ---
    if (tid < NCLS * FD) {
        int c = tid / FD, d = tid % FD;
        float s = 0.f;
        #pragma unroll
        for (int t = 0; t < 5; t++) s += fs[(c * 5 + t) * FD + d];
        supp[tid] = s * 0.2f;
    }
    if (tid < NQRY * FD / 4)
        ((float4*)qbuf)[tid] = ((const float4*)fq)[tid];
}

__device__ __forceinline__ const float* rowptr(const float* supp, const float* qbuf, int r) {
    return (r < NCLS) ? (supp + r * FD) : (qbuf + (r - NCLS) * FD);
}

// ---- fused: norms + S = fn@fn^T + f (normalized) + stable rank -> perm --------
// FIN variant: only writes out[j*5+i] = S[i][5+j]*scale  (grid = 5 blocks)
template<bool FIN>
__global__ void k_simrank(const float* __restrict__ supp, const float* __restrict__ qbuf,
                          float* __restrict__ f, float* __restrict__ nrm,
                          float* __restrict__ S, int* __restrict__ perm,
                          const float* __restrict__ scale, float* __restrict__ out) {
    __shared__ float fi[FD];
    __shared__ float row[NTOT];
    __shared__ float ssh[NTOT];
    int i = blockIdx.x;
    int t = threadIdx.x;                // 128
    const float* ri = rowptr(supp, qbuf, i);
    for (int u = t; u < FD; u += 128) fi[u] = ri[u];
    __syncthreads();
    float dot = 0.f;
    if (t < NTOT) {
        const float* rj = rowptr(supp, qbuf, t);
        float ss = 0.f;
        for (int k = 0; k < FD; k += 4) {
            float4 a = *(const float4*)(fi + k);
            float4 b = *(const float4*)(rj + k);
            dot += a.x * b.x + a.y * b.y + a.z * b.z + a.w * b.w;
            ss  += b.x * b.x + b.y * b.y + b.z * b.z + b.w * b.w;
        }
        ssh[t] = ss;
    }
    __syncthreads();
    float ni = fmaxf(sqrtf(ssh[i]), 1e-12f);
    float inv_i = 1.0f / ni;
    if (t < NTOT) {
        float nt = fmaxf(sqrtf(ssh[t]), 1e-12f);
        float val = dot * inv_i / nt;
        if (FIN) {
            if (t >= NCLS) out[(t - NCLS) * NCLS + i] = val * scale[0];
        } else {
            row[t] = val;
            S[i * NTOT + t] = val;
        }
    }
    if (FIN) return;
    __syncthreads();
    for (int u = t; u < FD; u += 128) f[i * FD + u] = fi[u] * inv_i;
    if (t == 0) { nrm[i] = ni; perm[i * 81] = i; }
    if (t < NCLS) {
        float v = row[t]; int rank = 0;
        for (int k = 0; k < NCLS; k++) {
            float w = row[k];
            if (w > v || (w == v && k < t)) rank++;
        }
        perm[i * 81 + 1 + rank] = t;
    } else if (t < NTOT) {
        int j = t - NCLS; float v = row[t]; int rank = 0;
        for (int k = NCLS; k < NTOT; k++) {
            float w = row[k];
            if (w > v || (w == v && (k - NCLS) < j)) rank++;
        }
        perm[i * 81 + 6 + rank] = t;
    }
}

// m -> (a,b): masked entries of 81x81, row-major; a in 0..5, b in a+1..80
__device__ __forceinline__ void mask_ab(int m, int& a, int& b) {
    int start = 0, len = 80, aa = 0;
    while (m >= start + len) { start += len; len--; aa++; }
    a = aa; b = aa + 1 + (m - start);
}

// ------- gather Xb[i][m] = bf16(S[p[a]][p[b]]) + zero Gs + zero P3 --------------
__global__ void k_gather(const float* __restrict__ S, const int* __restrict__ perm,
                         ushort* __restrict__ Xb, float* __restrict__ Gs,
                         float* __restrict__ P3) {
    __shared__ int p[81];
    int i = blockIdx.x;
    int t = threadIdx.x;                // 512
    if (t < 81) p[t] = perm[i * 81 + t];
    if (t < NTOT) Gs[i * NTOT + t] = 0.f;
    P3[i * NPAD + t] = 0.f;             // gemm3 accumulates atomically into P3
    __syncthreads();
    if (t < DNIN) {
        int a, b; mask_ab(t, a, b);
        Xb[i * KPAD + t] = f2bf(S[p[a] * NTOT + p[b]]);
    } else if (t < KPAD) {
        Xb[i * KPAD + t] = 0;
    }
}

// ------- wave-split-K MFMA GEMM, 8 waves/block, fused bias+relu+bf16 epilogue ---
// Block = 16 output cols x 80 rows x FULL K; 8 waves each take KPW ksteps
// (K = 8*KPW*32). 256 blocks x 8 waves = 8 waves/CU (matches split-K occupancy).
// B fragment-major -> every B load is a contiguous 1KB wave segment.
template<int KPW>
__global__ __launch_bounds__(512) void k_gemmws(
        const ushort* __restrict__ A, int lda,
        const ushort* __restrict__ Bf, int nks,
        const float* __restrict__ bias, ushort* __restrict__ H) {
    __shared__ v4f red[8][5][64];       // 40 KB
    int t = threadIdx.x;
    int w = t >> 6, lane = t & 63, l16 = lane & 15, quad = lane >> 4;
    int n0 = blockIdx.x * 16;
    int kc0 = w * (KPW * 32);
    const ushort* Ap = A + l16 * lda + kc0 + quad * 8;
    const ushort* Bp = Bf + ((size_t)blockIdx.x * nks + (kc0 >> 5)) * 512 + lane * 8;

    v4f acc[5];
    #pragma unroll
    for (int mt = 0; mt < 5; mt++) acc[mt] = (v4f){0.f, 0.f, 0.f, 0.f};

    #pragma unroll
    for (int s = 0; s < KPW; s++) {
        v8s a[5], b;
        #pragma unroll
        for (int mt = 0; mt < 5; mt++)
            a[mt] = *(const v8s*)(Ap + mt * 16 * lda + s * 32);
        b = *(const v8s*)(Bp + (size_t)s * 512);
        #pragma unroll
        for (int mt = 0; mt < 5; mt++)
            acc[mt] = __builtin_amdgcn_mfma_f32_16x16x32_bf16(a[mt], b, acc[mt], 0, 0, 0);
    }
    #pragma unroll
    for (int mt = 0; mt < 5; mt++) red[w][mt][lane] = acc[mt];
    __syncthreads();

    // reduce + epilogue: 1280 outputs (80 rows x 16 cols), 512 threads, 3 reps.
    // acc elem (mt,quad,r,l16): row = mt*16 + quad*4 + r, col = l16.
    #pragma unroll
    for (int j = 0; j < 3; j++) {
        int row = j * 32 + (t >> 4);
        if (row < 80) {
            int col = t & 15;
            int mt = row >> 4, rr = row & 15, qq = rr >> 2, r = rr & 3;
            int ln = qq * 16 + col;
            float v = 0.f;
            #pragma unroll
            for (int w2 = 0; w2 < 8; w2++) v += red[w2][mt][ln][r];
            v += bias[n0 + col];
            H[(size_t)row * HIDN + n0 + col] = f2bf(fmaxf(v, 0.f));
        }
    }
}

// ------- L3 GEMM: split-K, atomic-accumulate into single P3[80][512] -----------
// grid (8, 32) = 256 blocks x 256 threads (full chip). P3 pre-zeroed by k_gather.
__global__ __launch_bounds__(256) void k_gemm3(
        const ushort* __restrict__ A, int lda,
        const ushort* __restrict__ Bf, int nks,
        float* __restrict__ P3) {
    int tid = threadIdx.x;
    int w = tid >> 6, lane = tid & 63, l16 = lane & 15, quad = lane >> 4;
    int n0 = blockIdx.x * 64 + w * 16;
    int kc0 = blockIdx.y * 128;         // 4 ksteps per block
    const ushort* Ap = A + l16 * lda + kc0 + quad * 8;
    const ushort* Bp = Bf + ((size_t)(n0 >> 4) * nks + (kc0 >> 5)) * 512 + lane * 8;

    v4f acc[5];
    #pragma unroll
    for (int mt = 0; mt < 5; mt++) acc[mt] = (v4f){0.f, 0.f, 0.f, 0.f};

    #pragma unroll
    for (int s = 0; s < 4; s++) {
        v8s a[5], b;
        #pragma unroll
        for (int mt = 0; mt < 5; mt++)
            a[mt] = *(const v8s*)(Ap + mt * 16 * lda + s * 32);
        b = *(const v8s*)(Bp + (size_t)s * 512);
        #pragma unroll
        for (int mt = 0; mt < 5; mt++)
            acc[mt] = __builtin_amdgcn_mfma_f32_16x16x32_bf16(a[mt], b, acc[mt], 0, 0, 0);
    }
    int col = n0 + l16;
    #pragma unroll
    for (int mt = 0; mt < 5; mt++)
        #pragma unroll
        for (int r = 0; r < 4; r++)
            atomicAdd(&P3[(mt * 16 + quad * 4 + r) * NPAD + col], acc[mt][r]);
}

// ---------------- scatter-add VJP of the gather (single P3 + b3) ---------------
__global__ void k_scatter(const float* __restrict__ P3, const float* __restrict__ b3,
                          const int* __restrict__ perm, float* __restrict__ Gs) {
    __shared__ int p[81];
    int i = blockIdx.x;
    int t = threadIdx.x;                // 512
    if (t < 81) p[t] = perm[i * 81 + t];
    __syncthreads();
    if (t < DNIN) {
        float g = b3[t] + P3[i * NPAD + t];
        int a, b; mask_ab(t, a, b);
        atomicAdd(&Gs[p[a] * NTOT + p[b]], g);
    }
}

// ---- dfeat = (Gs+Gs^T) @ f ; dx = (dfeat - (dfeat.f) f)/n ; target -= LR*dx ----
__global__ void k_bwd(const float* __restrict__ Gs, const float* __restrict__ f,
                      const float* __restrict__ nrm, float* __restrict__ target,
                      int row0) {
    int r = row0 + blockIdx.x;
    __shared__ float cj[NTOT];
    __shared__ float red[2];
    int t = threadIdx.x;                // 128 threads, 5 elems each
    if (t < NTOT) cj[t] = Gs[r * NTOT + t] + Gs[t * NTOT + r];
    __syncthreads();
    float df[5] = {0.f, 0.f, 0.f, 0.f, 0.f};
    for (int j = 0; j < NTOT; j++) {
        float c = cj[j];
        const float* fj = f + j * FD;
        #pragma unroll
        for (int u = 0; u < 5; u++) df[u] += c * fj[t + 128 * u];
    }
    const float* fr = f + r * FD;
    float frv[5]; float partial = 0.f;
    #pragma unroll
    for (int u = 0; u < 5; u++) { frv[u] = fr[t + 128 * u]; partial += df[u] * frv[u]; }
    #pragma unroll
    for (int o = 32; o > 0; o >>= 1) partial += __shfl_xor(partial, o, 64);
    if ((t & 63) == 0) red[t >> 6] = partial;
    __syncthreads();
    float dot = red[0] + red[1];
    float invn = 1.0f / nrm[r];
    float* dst = target + blockIdx.x * FD;
    #pragma unroll
    for (int u = 0; u < 5; u++) {
        float dx = (df[u] - dot * frv[u]) * invn;
        dst[t + 128 * u] -= LRDNI * dx;
    }
}

extern "C" void kernel_launch(void* const* d_in, const int* in_sizes, int n_in,
                              void* d_out, int out_size, void* d_ws, size_t ws_size,
                              hipStream_t stream) {
    const float* fs    = (const float*)d_in[0];
    const float* fq    = (const float*)d_in[1];
    const float* scale = (const float*)d_in[2];
    const float* W[12];
    for (int i = 0; i < 12; i++) W[i] = (const float*)d_in[3 + i];
    // W[0..5] = ds_{W1,b1,W2,b2,W3,b3}; W[6..11] = dq_*

    float* base = (float*)d_ws;
    float* supp = base;                     // 3200
    float* qbuf = supp + 3200;              // 48000
    float* f    = qbuf + 48000;             // 51200
    float* nrm  = f + 51200;                // 96 (pad)
    float* S    = nrm + 96;                 // 6400
    int*   perm = (int*)(S + 6400);         // 6480 -> pad 6496
    float* P3   = (float*)(perm + 6496);    // 80*512 (single, atomically summed)
    float* Gs   = P3 + 80 * NPAD;           // 6400
    ushort* Xb  = (ushort*)(Gs + 6400);     // 80*512
    ushort* H1b = Xb + 80 * KPAD;           // 80*4096
    ushort* H2b = H1b + 80 * HIDN;          // 80*4096
    ushort* W1b_ds = H2b + 80 * HIDN;       // 4096*512 (frag-major)
    ushort* W1b_dq = W1b_ds + HIDN * KPAD;
    ushort* W3b_ds = W1b_dq + HIDN * KPAD;  // 512*4096 (frag-major)
    ushort* W3b_dq = W3b_ds + NPAD * HIDN;
    ushort* W2b_ds = W3b_dq + NPAD * HIDN;  // 4096*4096 (frag-major)
    ushort* W2b_dq = W2b_ds + (size_t)HIDN * HIDN;

    // grid MUST be exactly 2048 blocks (k_setup assumes 524288 threads)
    k_setup<<<2048, 256, 0, stream>>>(fs, fq, W[0], W[6], W[2], W[8], W[4], W[10],
                                      W1b_ds, W1b_dq, W2b_ds, W2b_dq, W3b_ds, W3b_dq,
                                      supp, qbuf);

    for (int step = 0; step < 3; step++) {
        for (int half = 0; half < 2; half++) {
            const float* const* w = (half == 0) ? W : (W + 6);
            const ushort* W1b = (half == 0) ? W1b_ds : W1b_dq;
            const ushort* W2b = (half == 0) ? W2b_ds : W2b_dq;
            const ushort* W3b = (half == 0) ? W3b_ds : W3b_dq;
            k_simrank<false><<<80, 128, 0, stream>>>(supp, qbuf, f, nrm, S, perm, nullptr, nullptr);
            k_gather<<<80, 512, 0, stream>>>(S, perm, Xb, Gs, P3);
            // L1: M=80 N=4096 K=512;  256 blocks x 8 waves, 2 ksteps/wave, epi->H1b
            k_gemmws<2><<<256, 512, 0, stream>>>(Xb, KPAD, W1b, 16, w[1], H1b);
            // L2: M=80 N=4096 K=4096; 256 blocks x 8 waves, 16 ksteps/wave, epi->H2b
            k_gemmws<16><<<256, 512, 0, stream>>>(H1b, HIDN, W2b, 128, w[3], H2b);
            // L3: M=80 N=512 K=4096;  grid(8,32)=256 blocks, atomic into P3
            k_gemm3<<<dim3(8, 32), 256, 0, stream>>>(H2b, HIDN, W3b, 128, P3);
            k_scatter<<<80, 512, 0, stream>>>(P3, w[5], perm, Gs);
            if (half == 0) k_bwd<<<5, 128, 0, stream>>>(Gs, f, nrm, supp, 0);
            else           k_bwd<<<75, 128, 0, stream>>>(Gs, f, nrm, qbuf, NCLS);
        }
    }
    k_simrank<true><<<5, 128, 0, stream>>>(supp, qbuf, f, nrm, S, perm, scale, (float*)d_out);
}